// Round 6
// baseline (83.764 us; speedup 1.0000x reference)
//
#include <hip/hip_runtime.h>

// Problem constants (from reference):
//   OUT=8192, GROUPS=64, GROUP_SIZE=128 -> weight flat: 8192*64*64 int32 (each
//   holds one byte = two int4 nibbles), scale flat: 8192*64 f32, out: 8192*8192 f32.
#define NW_TOTAL 33554432u          // packed int32 elements
#define N_PAIRS  (NW_TOTAL / 2u)    // 16777216 chunks of 2 packed ints
#define UNROLL   4

typedef int   iv2 __attribute__((ext_vector_type(2)));
typedef float fv4 __attribute__((ext_vector_type(4)));

__global__ __launch_bounds__(256)
void PackedINTSymmetricWeightsDecompressor_74440373174409_kernel(
        const int* __restrict__ w,
        const float* __restrict__ s,
        float* __restrict__ out)
{
    // Grid-stride with 4x inner unroll. Per inner step each instruction stays
    // wave-contiguous: loads cover 512 B/wave, stores 1 KiB/wave. The 4 loads
    // are issued back-to-back (independent) -> 4x outstanding VMEM per thread.
    const unsigned chunk  = gridDim.x * blockDim.x;       // pairs per unroll step
    const unsigned stride = chunk * UNROLL;
    const unsigned t0 = blockIdx.x * blockDim.x + threadIdx.x;

    for (unsigned t = t0; t < N_PAIRS; t += stride) {
        iv2   wv[UNROLL];
        float sc[UNROLL];
#pragma unroll
        for (int u = 0; u < UNROLL; ++u) {
            const unsigned idx = t + u * chunk;           // N_PAIRS % stride == 0
            wv[u] = *(reinterpret_cast<const iv2*>(w) + idx);
            sc[u] = s[idx >> 5];
        }
#pragma unroll
        for (int u = 0; u < UNROLL; ++u) {
            const unsigned idx = t + u * chunk;
            fv4 o;
            o.x = (float)(( wv[u].x       & 0xF) - 8) * sc[u];
            o.y = (float)(((wv[u].x >> 4) & 0xF) - 8) * sc[u];
            o.z = (float)(( wv[u].y       & 0xF) - 8) * sc[u];
            o.w = (float)(((wv[u].y >> 4) & 0xF) - 8) * sc[u];
            // nt store: write-once stream, skip L3 allocation (keeps weights
            // L3-resident). Pattern is wave-contiguous -> no partial lines.
            __builtin_nontemporal_store(o, reinterpret_cast<fv4*>(out) + idx);
        }
    }
}

extern "C" void kernel_launch(void* const* d_in, const int* in_sizes, int n_in,
                              void* d_out, int out_size, void* d_ws, size_t ws_size,
                              hipStream_t stream) {
    const int*   w   = (const int*)d_in[0];
    const float* s   = (const float*)d_in[1];
    float*       out = (float*)d_out;

    // N_PAIRS = 16777216 = 2048*256*32 -> evenly divided, 8 outer iters/thread.
    const int block = 256;
    const int grid  = 2048;
    PackedINTSymmetricWeightsDecompressor_74440373174409_kernel<<<grid, block, 0, stream>>>(w, s, out);
}

// Round 7
// 63.787 us; speedup vs baseline: 1.3132x; 1.3132x over previous
//
#include <hip/hip_runtime.h>

// Problem constants (from reference):
//   OUT=8192, GROUPS=64, GROUP_SIZE=128 -> weight flat: 8192*64*64 int32 (each
//   holds one byte = two int4 nibbles), scale flat: 8192*64 f32, out: 8192*8192 f32.
#define NW_TOTAL 33554432u          // packed int32 elements
#define N_PAIRS  (NW_TOTAL / 2u)    // 16777216 chunks of 2 packed ints
#define UNROLL   4
#define BLOCK    256u

typedef int   iv2 __attribute__((ext_vector_type(2)));
typedef float fv4 __attribute__((ext_vector_type(4)));

__global__ __launch_bounds__(256)
void PackedINTSymmetricWeightsDecompressor_74440373174409_kernel(
        const int* __restrict__ w,
        const float* __restrict__ s,
        float* __restrict__ out)
{
    // Block-LOCAL x4 unroll: each block owns a contiguous 1024-pair window per
    // outer iter; thread u-th load is only 2 KB from its (u-1)-th load, so the
    // 4 in-flight VMEM ops stay in the same DRAM pages (round 6 regression was
    // 8 MB-apart streams). Every instruction is wave-contiguous: loads 512 B,
    // stores 1 KiB.
    const unsigned per_block = BLOCK * UNROLL;            // 1024 pairs
    const unsigned tid = threadIdx.x;

    for (unsigned base = blockIdx.x * per_block + tid; base < N_PAIRS;
         base += gridDim.x * per_block) {
        iv2   wv[UNROLL];
        float sc[UNROLL];
#pragma unroll
        for (int u = 0; u < UNROLL; ++u) {
            const unsigned idx = base + u * BLOCK;        // N_PAIRS % (grid*per_block) == 0
            wv[u] = *(reinterpret_cast<const iv2*>(w) + idx);
            sc[u] = s[idx >> 5];
        }
#pragma unroll
        for (int u = 0; u < UNROLL; ++u) {
            const unsigned idx = base + u * BLOCK;
            fv4 o;
            o.x = (float)(( wv[u].x       & 0xF) - 8) * sc[u];
            o.y = (float)(((wv[u].x >> 4) & 0xF) - 8) * sc[u];
            o.z = (float)(( wv[u].y       & 0xF) - 8) * sc[u];
            o.w = (float)(((wv[u].y >> 4) & 0xF) - 8) * sc[u];
            // nt store: write-once stream, skip L3 allocation (keeps weights
            // L3-resident). Wave-contiguous -> no partial-line amplification.
            __builtin_nontemporal_store(o, reinterpret_cast<fv4*>(out) + idx);
        }
    }
}

extern "C" void kernel_launch(void* const* d_in, const int* in_sizes, int n_in,
                              void* d_out, int out_size, void* d_ws, size_t ws_size,
                              hipStream_t stream) {
    const int*   w   = (const int*)d_in[0];
    const float* s   = (const float*)d_in[1];
    float*       out = (float*)d_out;

    // 16777216 pairs = 2048 blocks * 1024 pairs * 8 outer iters -> even split.
    const int block = 256;
    const int grid  = 2048;
    PackedINTSymmetricWeightsDecompressor_74440373174409_kernel<<<grid, block, 0, stream>>>(w, s, out);
}

// Round 8
// 63.028 us; speedup vs baseline: 1.3290x; 1.0120x over previous
//
#include <hip/hip_runtime.h>

// Problem constants (from reference):
//   OUT=8192, GROUPS=64, GROUP_SIZE=128 -> weight flat: 8192*64*64 int32 (each
//   holds one byte = two int4 nibbles), scale flat: 8192*64 f32, out: 8192*8192 f32.
#define NW_TOTAL 33554432u          // packed int32 elements
#define N_PAIRS  (NW_TOTAL / 2u)    // 16777216 chunks of 2 packed ints
#define UNROLL   8
#define BLOCK    256u

typedef int   iv2 __attribute__((ext_vector_type(2)));
typedef float fv4 __attribute__((ext_vector_type(4)));

__global__ __launch_bounds__(256)
void PackedINTSymmetricWeightsDecompressor_74440373174409_kernel(
        const int* __restrict__ w,
        const float* __restrict__ s,
        float* __restrict__ out)
{
    // Block-LOCAL x8 unroll: each block owns a contiguous 2048-pair window per
    // outer iter; a thread's 8 loads are 2 KB apart (same DRAM pages), so the
    // 8 in-flight VMEM ops don't spread streams (round-6 lesson). Every
    // instruction is wave-contiguous: loads 512 B/wave, stores 1 KiB/wave.
    const unsigned per_block = BLOCK * UNROLL;            // 2048 pairs
    const unsigned tid = threadIdx.x;

    for (unsigned base = blockIdx.x * per_block + tid; base < N_PAIRS;
         base += gridDim.x * per_block) {
        iv2   wv[UNROLL];
        float sc[UNROLL];
#pragma unroll
        for (int u = 0; u < UNROLL; ++u) {
            const unsigned idx = base + u * BLOCK;        // even split, no tail
            wv[u] = *(reinterpret_cast<const iv2*>(w) + idx);
            sc[u] = s[idx >> 5];
        }
#pragma unroll
        for (int u = 0; u < UNROLL; ++u) {
            const unsigned idx = base + u * BLOCK;
            fv4 o;
            o.x = (float)(( wv[u].x       & 0xF) - 8) * sc[u];
            o.y = (float)(((wv[u].x >> 4) & 0xF) - 8) * sc[u];
            o.z = (float)(( wv[u].y       & 0xF) - 8) * sc[u];
            o.w = (float)(((wv[u].y >> 4) & 0xF) - 8) * sc[u];
            // nt store: write-once stream, skip L3 allocation (keeps weights
            // L3-resident). Wave-contiguous -> no partial-line amplification.
            __builtin_nontemporal_store(o, reinterpret_cast<fv4*>(out) + idx);
        }
    }
}

extern "C" void kernel_launch(void* const* d_in, const int* in_sizes, int n_in,
                              void* d_out, int out_size, void* d_ws, size_t ws_size,
                              hipStream_t stream) {
    const int*   w   = (const int*)d_in[0];
    const float* s   = (const float*)d_in[1];
    float*       out = (float*)d_out;

    // 16777216 pairs = 2048 blocks * 2048 pairs * 4 outer iters -> even split.
    const int block = 256;
    const int grid  = 2048;
    PackedINTSymmetricWeightsDecompressor_74440373174409_kernel<<<grid, block, 0, stream>>>(w, s, out);
}